// Round 2
// baseline (1678.432 us; speedup 1.0000x reference)
//
#include <hip/hip_runtime.h>

#define B_   128
#define NO_  256
#define NR_  512
#define D_   1024

typedef __bf16 bf16x8 __attribute__((ext_vector_type(8)));
typedef float  f32x4  __attribute__((ext_vector_type(4)));

__device__ __forceinline__ unsigned short f2b(float f){   // fp32 -> bf16 RNE
  unsigned int u = __float_as_uint(f);
  unsigned int r = (u + 0x7fffu + ((u >> 16) & 1u)) >> 16;
  return (unsigned short)r;
}

// ---------------- fp32 -> bf16 flat convert (8 elems/thread) ----------------
__global__ void conv_f32_bf16(const float4* __restrict__ in, uint4* __restrict__ out, int n8){
  int i = blockIdx.x * blockDim.x + threadIdx.x;
  if (i >= n8) return;
  float4 a = in[2*i], b = in[2*i+1];
  union { unsigned short s[8]; uint4 v; } p;
  p.s[0]=f2b(a.x); p.s[1]=f2b(a.y); p.s[2]=f2b(a.z); p.s[3]=f2b(a.w);
  p.s[4]=f2b(b.x); p.s[5]=f2b(b.y); p.s[6]=f2b(b.z); p.s[7]=f2b(b.w);
  out[i] = p.v;
}

// ---------------- copy fp32 obj -> out0 (uint4 = 4 floats) ----------------
__global__ void copy_vec4(const uint4* __restrict__ in, uint4* __restrict__ out, int n){
  int i = blockIdx.x * blockDim.x + threadIdx.x;
  if (i < n) out[i] = in[i];
}

// ---------------- transpose + convert: fp32 [R][C] -> bf16 [C][R] ----------------
__global__ void transpose_f32_bf16(const float* __restrict__ in,
                                   unsigned short* __restrict__ out, int R, int C){
  __shared__ unsigned short tile[32][33];
  int tx = threadIdx.x, ty = threadIdx.y;       // 32 x 8
  int x  = blockIdx.x * 32 + tx;
  int y0 = blockIdx.y * 32;
  #pragma unroll
  for (int i = 0; i < 4; i++) tile[ty + i*8][tx] = f2b(in[(size_t)(y0 + ty + i*8) * C + x]);
  __syncthreads();
  int ox  = y0 + tx;
  int oy0 = blockIdx.x * 32;
  #pragma unroll
  for (int i = 0; i < 4; i++) out[(size_t)(oy0 + ty + i*8) * R + ox] = tile[tx][ty + i*8];
}

// ---------------- fused GEMM (bf16 MFMA, fp32 epilogue) ----------------
// MODE 0: A = [obj_b | attr_b]            (K=2048), out = relu(A@W+b)+attr_f
// MODE 1: A = [obj_b[s] | rela_b | obj_b[o]] (K=3072), out = (relu(A@W+b)+rela_f)*mask
// WT: bf16 W transposed [N=1024][K]. xres_f: fp32 residual. All A sources bf16.
template<int MODE>
__global__ void gemm_fused(const unsigned short* __restrict__ objb,
                           const unsigned short* __restrict__ xresb,
                           const float* __restrict__ xresf,
                           const int* __restrict__ edges,
                           const float* __restrict__ mask,
                           const unsigned short* __restrict__ WT,
                           const float* __restrict__ bias,
                           float* __restrict__ out)
{
  constexpr int K   = MODE ? 3*D_ : 2*D_;
  constexpr int LDA = 72;                       // 64 + 8 pad (bank spread, 16B aligned)
  __shared__ unsigned short Asm[128*LDA];       // 18 KB
  __shared__ unsigned short Bsm[128*LDA];       // 18 KB

  const int t  = threadIdx.x;
  const int l  = t & 63;
  const int w  = t >> 6;
  const int wr = w >> 1, wc = w & 1;            // 2x2 wave grid, 64x64 each
  const int m0 = blockIdx.y * 128;
  const int n0 = blockIdx.x * 128;

  // staging coords: thread covers rows {i*32+sr}, cols [sc, sc+8)
  const int sr = t >> 3;
  const int sc = (t & 7) * 8;

  const unsigned short* pA0[4];
  const unsigned short* pA1[4];
  const unsigned short* pA2[4];
  #pragma unroll
  for (int i = 0; i < 4; i++){
    int m = m0 + i*32 + sr;
    if (MODE == 0){
      pA0[i] = objb  + (size_t)m * D_;          // obj half
      pA1[i] = xresb + (size_t)m * D_;          // attr half
      pA2[i] = nullptr;
    } else {
      int b = m >> 9;                           // m / NR_
      int s = edges[2*m];
      int o = edges[2*m + 1];
      pA0[i] = objb  + (size_t)((b << 8) + s) * D_;   // b*NO_ + s
      pA1[i] = xresb + (size_t)m * D_;                // rela_bf16
      pA2[i] = objb  + (size_t)((b << 8) + o) * D_;
    }
  }
  const unsigned short* pB[4];
  #pragma unroll
  for (int i = 0; i < 4; i++) pB[i] = WT + (size_t)(n0 + i*32 + sr) * K;

  f32x4 acc[4][4];
  #pragma unroll
  for (int x = 0; x < 4; x++)
    #pragma unroll
    for (int y = 0; y < 4; y++) acc[x][y] = (f32x4){0.f,0.f,0.f,0.f};

  const int kq = (l >> 4) * 8;                  // k sub-offset of this lane-quad
  const int fr = l & 15;                        // fragment row/col

  for (int k0 = 0; k0 < K; k0 += 64){
    #pragma unroll
    for (int i = 0; i < 4; i++){
      const unsigned short* ga;
      if (MODE == 0){
        ga = (k0 < D_) ? pA0[i] + k0 : pA1[i] + (k0 - D_);
      } else {
        ga = (k0 < D_)   ? pA0[i] + k0
           : (k0 < 2*D_) ? pA1[i] + (k0 - D_)
           :               pA2[i] + (k0 - 2*D_);
      }
      *(uint4*)&Asm[(i*32 + sr) * LDA + sc] = *(const uint4*)(ga + sc);
      *(uint4*)&Bsm[(i*32 + sr) * LDA + sc] = *(const uint4*)(pB[i] + k0 + sc);
    }
    __syncthreads();

    #pragma unroll
    for (int ks = 0; ks < 2; ks++){
      bf16x8 af[4], bfv[4];
      #pragma unroll
      for (int x = 0; x < 4; x++)
        af[x]  = *(const bf16x8*)&Asm[(wr*64 + x*16 + fr) * LDA + ks*32 + kq];
      #pragma unroll
      for (int y = 0; y < 4; y++)
        bfv[y] = *(const bf16x8*)&Bsm[(wc*64 + y*16 + fr) * LDA + ks*32 + kq];
      #pragma unroll
      for (int x = 0; x < 4; x++)
        #pragma unroll
        for (int y = 0; y < 4; y++)
          acc[x][y] = __builtin_amdgcn_mfma_f32_16x16x32_bf16(af[x], bfv[y], acc[x][y], 0, 0, 0);
    }
    __syncthreads();
  }

  // epilogue: bias + relu + fp32 residual (+ mask), fp32 out
  const int colb = n0 + wc*64 + fr;
  float bv[4];
  #pragma unroll
  for (int y = 0; y < 4; y++) bv[y] = bias[colb + y*16];

  const int rowb = m0 + wr*64 + ((l >> 4) << 2);
  #pragma unroll
  for (int x = 0; x < 4; x++){
    #pragma unroll
    for (int i = 0; i < 4; i++){
      int gr = rowb + x*16 + i;
      float mk = 1.f;
      if (MODE == 1) mk = mask[gr];
      size_t rbase = (size_t)gr * D_;
      #pragma unroll
      for (int y = 0; y < 4; y++){
        int gc = colb + y*16;
        float v = acc[x][y][i] + bv[y];
        v = fmaxf(v, 0.f) + xresf[rbase + gc];
        if (MODE == 1) v *= mk;
        out[rbase + gc] = v;
      }
    }
  }
}

extern "C" void kernel_launch(void* const* d_in, const int* in_sizes, int n_in,
                              void* d_out, int out_size, void* d_ws, size_t ws_size,
                              hipStream_t stream){
  const float* obj   = (const float*)d_in[0];
  const float* attr  = (const float*)d_in[1];
  const float* rela  = (const float*)d_in[2];
  const int*   edges = (const int*)d_in[3];
  const float* masks = (const float*)d_in[4];
  const float* Wa    = (const float*)d_in[5];
  const float* ba    = (const float*)d_in[6];
  const float* Wr    = (const float*)d_in[7];
  const float* br    = (const float*)d_in[8];

  const size_t NOBJ  = (size_t)B_*NO_*D_;   // 33,554,432
  const size_t NRELA = (size_t)B_*NR_*D_;   // 67,108,864

  float* out0 = (float*)d_out;
  float* out1 = out0 + NOBJ;
  float* out2 = out1 + NOBJ;

  // bf16 scratch carved out of d_out regions (stream-ordered lifetimes):
  //   out0 region: obj_bf16 (64MB) + attr_bf16 (64MB)  — consumed by gemm0/gemm1, then overwritten by final obj copy
  //   out1 region: rela_bf16 (128MB)                    — consumed by gemm1, then overwritten by gemm0's output
  unsigned short* objb  = (unsigned short*)d_out;
  unsigned short* attrb = objb + NOBJ;
  unsigned short* relab = (unsigned short*)(out1);
  // W transposes (bf16) in ws: 4MB + 6MB
  unsigned short* WTa = (unsigned short*)d_ws;            // [1024][2048]
  unsigned short* WTr = WTa + (size_t)1024*2048;          // [1024][3072]

  conv_f32_bf16<<<(int)(NOBJ/8/256),  256, 0, stream>>>((const float4*)obj,  (uint4*)objb,  (int)(NOBJ/8));
  conv_f32_bf16<<<(int)(NOBJ/8/256),  256, 0, stream>>>((const float4*)attr, (uint4*)attrb, (int)(NOBJ/8));
  conv_f32_bf16<<<(int)(NRELA/8/256), 256, 0, stream>>>((const float4*)rela, (uint4*)relab, (int)(NRELA/8));

  transpose_f32_bf16<<<dim3(1024/32, 2048/32), dim3(32,8), 0, stream>>>(Wa, WTa, 2048, 1024);
  transpose_f32_bf16<<<dim3(1024/32, 3072/32), dim3(32,8), 0, stream>>>(Wr, WTr, 3072, 1024);

  // gemm1 FIRST (reads relab in out1 region), then gemm0 (overwrites out1), then obj copy (overwrites out0 scratch)
  gemm_fused<1><<<dim3(8, (B_*NR_)/128), 256, 0, stream>>>(objb, relab, rela, edges, masks, WTr, br, out2);
  gemm_fused<0><<<dim3(8, (B_*NO_)/128), 256, 0, stream>>>(objb, attrb, attr, nullptr, nullptr, WTa, ba, out1);

  int nv = (int)(NOBJ / 4);                                // uint4 = 4 floats
  copy_vec4<<<nv/256, 256, 0, stream>>>((const uint4*)obj, (uint4*)out0, nv);
}